// Round 4
// baseline (72.355 us; speedup 1.0000x reference)
//
#include <hip/hip_runtime.h>

// exp[n,h] = sum_{i<48,j<48} obs_re[h,i,j] * x[n,i] * x[n,j]
// (psi real => Im part cancels; obs_im unused; padding i,j>=48 zero)
//
// Fused kernel, 512-thread blocks (8 waves), 256 tokens/block, grid 256.
// Per block: obs_re -> bf16 A-frags in LDS (48 KB, staged once, reused by
// 8 waves x 2 groups); x tile 256 tokens bf16 in LDS (28 KB, stride 112 B).
// Per wave: 2 token-groups x 8 heads via mfma_f32_16x16x32_bf16, epilogue
// dot + 2 shfl_xor, coalesced float4 stores.
// __launch_bounds__(512,4): 2 blocks/CU (76 KB LDS), 16 waves/CU, VGPR<=128.

#define NTOK 65536
#define NHEAD 8
#define XSTRIDE 56           // shorts per x-row (48 data + 8 pad) = 112 B
#define TPB_TOK 256          // tokens per block
#define NTHREADS 512

typedef __attribute__((ext_vector_type(8))) short short8;
typedef __attribute__((ext_vector_type(4))) short short4v;
typedef __attribute__((ext_vector_type(4))) float float4v;

static __device__ __forceinline__ short f2bf(float f) {
    unsigned int u = __builtin_bit_cast(unsigned int, f);
    u += 0x7FFFu + ((u >> 16) & 1u);        // round-to-nearest-even
    return (short)(u >> 16);
}
static __device__ __forceinline__ float bf2f(short s) {
    return __builtin_bit_cast(float, ((unsigned int)(unsigned short)s) << 16);
}

__global__ __launch_bounds__(NTHREADS, 4) void qform_fused(
    const float* __restrict__ x,        // (65536, 48)
    const float* __restrict__ obs,      // (8, 64, 64)
    float* __restrict__ out)            // (65536, 8)
{
    __shared__ short a_lds[48 * 64 * 8];        // 48 frags x 64 lanes x 16 B = 48 KB
    __shared__ short xl[TPB_TOK * XSTRIDE];     // 28 KB

    const int tid  = threadIdx.x;
    const int w    = tid >> 6, lane = tid & 63;
    const int q    = lane >> 4, c = lane & 15;
    const int tb   = blockIdx.x * TPB_TOK;

    // ---- issue x-tile HBM loads first (long latency), then obs L2 loads ----
    float4 xv[6];
    #pragma unroll
    for (int s = 0; s < 6; ++s)
        xv[s] = ((const float4*)x)[(size_t)tb * 12 + s * NTHREADS + tid];

    // A-frags: frag f = h*6 + kt*3 + it; lane (q,c) holds
    // A[m=c][k=8q+jj] = obs[h][16it+c][32kt+8q+jj]   (validated rounds 2-3)
    #pragma unroll
    for (int u = 0; u < 6; ++u) {
        int f = u * 8 + w;                      // wave w stages frags w, w+8, ...
        int h = f / 6, rem = f % 6, kt = rem / 3, it = rem % 3;
        const float4* src = (const float4*)(obs +
            ((size_t)(h * 64 + 16 * it + c) * 64 + 32 * kt + 8 * q));
        float4 v0 = src[0], v1 = src[1];
        short8 a;
        a[0] = f2bf(v0.x); a[1] = f2bf(v0.y); a[2] = f2bf(v0.z); a[3] = f2bf(v0.w);
        a[4] = f2bf(v1.x); a[5] = f2bf(v1.y); a[6] = f2bf(v1.z); a[7] = f2bf(v1.w);
        *(short8*)(a_lds + ((size_t)f * 64 + lane) * 8) = a;
    }

    // x tile -> LDS bf16
    #pragma unroll
    for (int s = 0; s < 6; ++s) {
        int idx = s * NTHREADS + tid;           // 0..3071 float4 chunks
        int t = idx / 12, ch = idx % 12;
        short4v b;
        b.x = f2bf(xv[s].x); b.y = f2bf(xv[s].y); b.z = f2bf(xv[s].z); b.w = f2bf(xv[s].w);
        *(short4v*)(xl + t * XSTRIDE + ch * 4) = b;
    }
    __syncthreads();

    // ---- per-wave compute: 2 groups of 16 tokens ----
    short8 bfr[2][2];
    float  xe[2][3][4];
    #pragma unroll
    for (int g = 0; g < 2; ++g) {
        const int row = w * 32 + g * 16 + c;    // token within block
        bfr[g][0] = *(const short8*)(xl + row * XSTRIDE + q * 8);
        if (q < 2)
            bfr[g][1] = *(const short8*)(xl + row * XSTRIDE + 32 + q * 8);
        else
            bfr[g][1] = (short8)0;              // j >= 48: psi-pad is zero
        #pragma unroll
        for (int it = 0; it < 3; ++it)
            #pragma unroll
            for (int r = 0; r < 4; ++r)
                xe[g][it][r] = bf2f(xl[row * XSTRIDE + 16 * it + 4 * q + r]);
    }

    float ph[2][NHEAD];
    #pragma unroll
    for (int h = 0; h < NHEAD; ++h) {
        short8 A[6];
        #pragma unroll
        for (int u = 0; u < 6; ++u)
            A[u] = *(const short8*)(a_lds + ((size_t)(h * 6 + u) * 64 + lane) * 8);
        #pragma unroll
        for (int g = 0; g < 2; ++g) {
            float4v acc[3];
            #pragma unroll
            for (int it = 0; it < 3; ++it) {
                float4v z = {0.f, 0.f, 0.f, 0.f};
                acc[it] = __builtin_amdgcn_mfma_f32_16x16x32_bf16(A[it],     bfr[g][0], z,       0, 0, 0);
                acc[it] = __builtin_amdgcn_mfma_f32_16x16x32_bf16(A[3 + it], bfr[g][1], acc[it], 0, 0, 0);
            }
            float p = 0.f;
            #pragma unroll
            for (int it = 0; it < 3; ++it)
                #pragma unroll
                for (int r = 0; r < 4; ++r)
                    p += acc[it][r] * xe[g][it][r];   // x[row][16it+4q+r] * D[i][row]
            p += __shfl_xor(p, 16, 64);               // reduce over q (i mod-16)
            p += __shfl_xor(p, 32, 64);
            ph[g][h] = p;
        }
    }

    // ---- coalesced store: lanes 0..15 each own one token per group ----
    if (lane < 16) {
        #pragma unroll
        for (int g = 0; g < 2; ++g) {
            float4* o4 = (float4*)(out + (size_t)(tb + w * 32 + g * 16 + c) * NHEAD);
            o4[0] = make_float4(ph[g][0], ph[g][1], ph[g][2], ph[g][3]);
            o4[1] = make_float4(ph[g][4], ph[g][5], ph[g][6], ph[g][7]);
        }
    }
}

extern "C" void kernel_launch(void* const* d_in, const int* in_sizes, int n_in,
                              void* d_out, int out_size, void* d_ws, size_t ws_size,
                              hipStream_t stream) {
    const float* x      = (const float*)d_in[0];   // (16,4096,48)
    const float* obs_re = (const float*)d_in[1];   // (8,64,64)
    // d_in[2] = obs_im: unused (Re(psi^H O psi) with real psi)
    float* out = (float*)d_out;                    // (16,4096,8)

    qform_fused<<<NTOK / TPB_TOK, NTHREADS, 0, stream>>>(x, obs_re, out);
}